// Round 10
// baseline (1482.949 us; speedup 1.0000x reference)
//
#include <hip/hip_runtime.h>

typedef float v2f __attribute__((ext_vector_type(2)));
typedef float v4f __attribute__((ext_vector_type(4)));

#define T_STEPS 2048
#define BATCH   2
#define IDIM    40
#define HDIM    44
#define GDIM    176      // 4*H
#define ADIM    262144
#define EDIM    88       // 2*H
#define NEG_L   (-1.4426950408889634f)   // -log2(e)
#define NEG_2L  (-2.8853900817779268f)   // -2*log2(e)

// K1: xproj[t][b][gi] = scale(gi) * (b_ih[gi] + b_hh[gi] + x[t][b]·W_ih[gi])
__global__ __launch_bounds__(192) void xproj_kernel(
    const float* __restrict__ x,      // [T][B][40]
    const float* __restrict__ W_ih,   // [176][40]
    const float* __restrict__ b_ih,   // [176]
    const float* __restrict__ b_hh,   // [176]
    float* __restrict__ xproj)        // [T][B][176]
{
    const int tb = blockIdx.x;        // t*B + b
    const int gi = threadIdx.x;
    __shared__ __align__(16) float xs[IDIM];
    if (threadIdx.x < IDIM) xs[threadIdx.x] = x[(size_t)tb * IDIM + threadIdx.x];
    __syncthreads();
    if (gi < GDIM) {
        const float* wr = W_ih + gi * IDIM;
        float a0 = 0.f, a1 = 0.f;
        #pragma unroll
        for (int i = 0; i < IDIM; i += 4) {
            float4 wv = *(const float4*)&wr[i];
            float4 xv = *(const float4*)&xs[i];
            a0 += wv.x * xv.x + wv.z * xv.z;
            a1 += wv.y * xv.y + wv.w * xv.w;
        }
        const float scale = (gi >= 2 * HDIM && gi < 3 * HDIM) ? NEG_2L : NEG_L;
        xproj[(size_t)tb * GDIM + gi] = scale * (a0 + a1 + b_ih[gi] + b_hh[gi]);
    }
}

// K2: serial LSTM, BOTH batches in ONE wave (single block). Lane j owns unit
// j's 4 gate rows (shared weights) and h/c for batch A AND batch B. The two
// batches' dot products, nonlinearity chains, and LDS round-trips are
// independent -> they fill each other's dependency stalls (r8 proved clock
// is 2.4GHz and the 795cyc/step gap is exposed single-wave stalls).
// Barrier-free LDS broadcast (r7), exp2-folded gates (r6), 2-deep prefetch.
__global__ __launch_bounds__(64)
__attribute__((amdgpu_waves_per_eu(1, 1)))
void lstm_kernel(
    const float* __restrict__ xproj,  // [T][B][176] (pre-scaled)
    const float* __restrict__ h0,     // [1][B][44]
    const float* __restrict__ c0,     // [1][B][44]
    const float* __restrict__ W_hh,   // [176][44]
    const float* __restrict__ W_v,    // [1][128]
    const float* __restrict__ b_v,    // [1]
    float* __restrict__ base_out)     // [B]
{
    const int j = threadIdx.x;          // 0..63; lanes >= 44 are passengers
    const int jj = (j < HDIM) ? j : (HDIM - 1);   // clamped (no OOB)

    __shared__ __align__(16) float hA_sh[64];
    __shared__ __align__(16) float hB_sh[64];

    // Per-lane weight rows, pre-scaled once (shared by both batches)
    v2f wi[22], wf[22], wg[22], wo[22];
    {
        const float* ri = W_hh + (size_t)jj * HDIM;
        const float* rf = W_hh + (size_t)(HDIM + jj) * HDIM;
        const float* rg = W_hh + (size_t)(2 * HDIM + jj) * HDIM;
        const float* ro = W_hh + (size_t)(3 * HDIM + jj) * HDIM;
        #pragma unroll
        for (int k = 0; k < 22; ++k) {
            wi[k] = ((const v2f*)ri)[k] * NEG_L;
            wf[k] = ((const v2f*)rf)[k] * NEG_L;
            wg[k] = ((const v2f*)rg)[k] * NEG_2L;
            wo[k] = ((const v2f*)ro)[k] * NEG_L;
        }
    }

    float cA = c0[jj];
    float cB = c0[HDIM + jj];
    hA_sh[j] = (j < HDIM) ? h0[j] : 0.f;          // same-wave in-order DS
    hB_sh[j] = (j < HDIM) ? h0[HDIM + j] : 0.f;

    v2f hpA[22], hpB[22];
    #pragma unroll
    for (int k = 0; k < 11; ++k) {
        v4f tA = ((const v4f*)hA_sh)[k];
        hpA[2 * k]     = __builtin_shufflevector(tA, tA, 0, 1);
        hpA[2 * k + 1] = __builtin_shufflevector(tA, tA, 2, 3);
        v4f tB = ((const v4f*)hB_sh)[k];
        hpB[2 * k]     = __builtin_shufflevector(tB, tB, 0, 1);
        hpB[2 * k + 1] = __builtin_shufflevector(tB, tB, 2, 3);
    }

    const float* xpA = xproj;          // batch A: step stride 352
    const float* xpB = xproj + GDIM;   // batch B
    #define LDX(base, dst, s) { const float* _a = (base) + (size_t)(s) * (BATCH * GDIM); \
        dst##0 = _a[jj]; dst##1 = _a[HDIM + jj]; dst##2 = _a[2 * HDIM + jj]; dst##3 = _a[3 * HDIM + jj]; }
    float rA0, rA1, rA2, rA3, pA0, pA1, pA2, pA3;
    float rB0, rB1, rB2, rB3, pB0, pB1, pB2, pB3;
    LDX(xpA, rA, 0) LDX(xpA, pA, 1)
    LDX(xpB, rB, 0) LDX(xpB, pB, 1)

    float hvalA = 0.f, hvalB = 0.f;

    #pragma unroll 1
    for (int step = 0; step < T_STEPS; ++step) {
        // fused FMA block: 8 independent single chains (4 gates x 2 batches)
        v2f aiA = (v2f)(0.f), afA = (v2f)(0.f), agA = (v2f)(0.f), aoA = (v2f)(0.f);
        v2f aiB = (v2f)(0.f), afB = (v2f)(0.f), agB = (v2f)(0.f), aoB = (v2f)(0.f);
        #pragma unroll
        for (int k = 0; k < 22; ++k) {
            aiA = __builtin_elementwise_fma(wi[k], hpA[k], aiA);
            aiB = __builtin_elementwise_fma(wi[k], hpB[k], aiB);
            afA = __builtin_elementwise_fma(wf[k], hpA[k], afA);
            afB = __builtin_elementwise_fma(wf[k], hpB[k], afB);
            agA = __builtin_elementwise_fma(wg[k], hpA[k], agA);
            agB = __builtin_elementwise_fma(wg[k], hpB[k], agB);
            aoA = __builtin_elementwise_fma(wo[k], hpA[k], aoA);
            aoB = __builtin_elementwise_fma(wo[k], hpB[k], aoB);
        }

        // batch A tail
        float yiA = aiA.x + aiA.y + rA0;
        float yfA = afA.x + afA.y + rA1;
        float ygA = agA.x + agA.y + rA2;
        float yoA = aoA.x + aoA.y + rA3;
        float s_iA = __builtin_amdgcn_rcpf(1.0f + __builtin_amdgcn_exp2f(yiA));
        float s_fA = __builtin_amdgcn_rcpf(1.0f + __builtin_amdgcn_exp2f(yfA));
        float w_gA = __builtin_amdgcn_rcpf(1.0f + __builtin_amdgcn_exp2f(ygA));
        float s_oA = __builtin_amdgcn_rcpf(1.0f + __builtin_amdgcn_exp2f(yoA));
        float t_gA = __builtin_fmaf(2.0f, w_gA, -1.0f);
        cA = s_fA * cA + s_iA * t_gA;
        float w_cA = __builtin_amdgcn_rcpf(1.0f + __builtin_amdgcn_exp2f(cA * NEG_2L));
        hvalA = __builtin_fmaf(s_oA + s_oA, w_cA, -s_oA);
        hA_sh[j] = hvalA;

        // batch B tail (independent -> fills A's chain stalls)
        float yiB = aiB.x + aiB.y + rB0;
        float yfB = afB.x + afB.y + rB1;
        float ygB = agB.x + agB.y + rB2;
        float yoB = aoB.x + aoB.y + rB3;
        float s_iB = __builtin_amdgcn_rcpf(1.0f + __builtin_amdgcn_exp2f(yiB));
        float s_fB = __builtin_amdgcn_rcpf(1.0f + __builtin_amdgcn_exp2f(yfB));
        float w_gB = __builtin_amdgcn_rcpf(1.0f + __builtin_amdgcn_exp2f(ygB));
        float s_oB = __builtin_amdgcn_rcpf(1.0f + __builtin_amdgcn_exp2f(yoB));
        float t_gB = __builtin_fmaf(2.0f, w_gB, -1.0f);
        cB = s_fB * cB + s_iB * t_gB;
        float w_cB = __builtin_amdgcn_rcpf(1.0f + __builtin_amdgcn_exp2f(cB * NEG_2L));
        hvalB = __builtin_fmaf(s_oB + s_oB, w_cB, -s_oB);
        hB_sh[j] = hvalB;

        // re-broadcast both h vectors (in-order DS, no barrier)
        #pragma unroll
        for (int k = 0; k < 11; ++k) {
            v4f tA = ((const v4f*)hA_sh)[k];
            hpA[2 * k]     = __builtin_shufflevector(tA, tA, 0, 1);
            hpA[2 * k + 1] = __builtin_shufflevector(tA, tA, 2, 3);
        }
        #pragma unroll
        for (int k = 0; k < 11; ++k) {
            v4f tB = ((const v4f*)hB_sh)[k];
            hpB[2 * k]     = __builtin_shufflevector(tB, tB, 0, 1);
            hpB[2 * k + 1] = __builtin_shufflevector(tB, tB, 2, 3);
        }

        // rotate prefetch (2-deep, both batches)
        rA0 = pA0; rA1 = pA1; rA2 = pA2; rA3 = pA3;
        rB0 = pB0; rB1 = pB1; rB2 = pB2; rB3 = pB3;
        const int ns = (step + 2 < T_STEPS) ? step + 2 : (T_STEPS - 1);
        LDX(xpA, pA, ns)
        LDX(xpB, pB, ns)
    }
    #undef LDX

    // epilogue: base[b] = sum_j h[j]*Wv[j] + c[j]*Wv[44+j] + b_v
    float pA = 0.f, pB = 0.f;
    if (j < HDIM) {
        pA = hvalA * W_v[j] + cA * W_v[HDIM + j];
        pB = hvalB * W_v[j] + cB * W_v[HDIM + j];
    }
    #pragma unroll
    for (int off = 32; off; off >>= 1) {
        pA += __shfl_down(pA, off);
        pB += __shfl_down(pB, off);
    }
    if (j == 0) {
        base_out[0] = pA + b_v[0];
        base_out[1] = pB + b_v[0];
    }
}

// K3: out[b][a] = (a < len[b]) ? base[b] + action[b][a][:].w_a : 0
__global__ __launch_bounds__(256) void action_kernel(
    const float* __restrict__ action,     // [B][A][40]
    const int*   __restrict__ act_length, // [B]
    const float* __restrict__ W_v,        // [1][128]; w_a = W_v[88..127]
    const float* __restrict__ base,       // [B]
    float* __restrict__ out)              // [B][A]
{
    const int idx = blockIdx.x * 256 + threadIdx.x;   // 0 .. B*A-1
    const int b = idx >> 18;                          // A = 2^18
    const int a = idx & (ADIM - 1);
    if (a >= act_length[b]) { out[idx] = 0.f; return; }
    const float* row = action + (size_t)idx * IDIM;
    float a0 = 0.f, a1 = 0.f;
    #pragma unroll
    for (int i = 0; i < IDIM; i += 4) {
        float4 av = *(const float4*)&row[i];
        a0 += av.x * W_v[EDIM + i + 0] + av.z * W_v[EDIM + i + 2];
        a1 += av.y * W_v[EDIM + i + 1] + av.w * W_v[EDIM + i + 3];
    }
    out[idx] = base[b] + a0 + a1;
}

extern "C" void kernel_launch(void* const* d_in, const int* in_sizes, int n_in,
                              void* d_out, int out_size, void* d_ws, size_t ws_size,
                              hipStream_t stream) {
    const float* x        = (const float*)d_in[0];
    const float* h0       = (const float*)d_in[1];
    const float* c0       = (const float*)d_in[2];
    const float* action   = (const float*)d_in[3];
    const int*   act_len  = (const int*)  d_in[4];
    const float* W_ih     = (const float*)d_in[5];
    const float* W_hh     = (const float*)d_in[6];
    const float* b_ih     = (const float*)d_in[7];
    const float* b_hh     = (const float*)d_in[8];
    const float* W_v      = (const float*)d_in[9];
    const float* b_v      = (const float*)d_in[10];
    float* out = (float*)d_out;

    float* xproj = (float*)d_ws;                                   // [T][B][176]
    float* base  = xproj + (size_t)T_STEPS * BATCH * GDIM;         // B floats

    xproj_kernel<<<dim3(T_STEPS * BATCH), dim3(192), 0, stream>>>(
        x, W_ih, b_ih, b_hh, xproj);
    lstm_kernel<<<dim3(1), dim3(64), 0, stream>>>(
        xproj, h0, c0, W_hh, W_v, b_v, base);
    action_kernel<<<dim3((BATCH * ADIM) / 256), dim3(256), 0, stream>>>(
        action, act_len, W_v, base, out);
}

// Round 11
// 641.252 us; speedup vs baseline: 2.3126x; 2.3126x over previous
//
#include <hip/hip_runtime.h>

typedef float v2f __attribute__((ext_vector_type(2)));
typedef float v4f __attribute__((ext_vector_type(4)));

#define T_STEPS 2048
#define BATCH   2
#define IDIM    40
#define HDIM    44
#define GDIM    176      // 4*H
#define ADIM    262144
#define EDIM    88       // 2*H
#define NEG_L   (-1.4426950408889634f)   // -log2(e)
#define NEG_2L  (-2.8853900817779268f)   // -2*log2(e)

// K1: xproj[t][b][gi] = scale(gi) * (b_ih[gi] + b_hh[gi] + x[t][b]·W_ih[gi])
__global__ __launch_bounds__(192) void xproj_kernel(
    const float* __restrict__ x,      // [T][B][40]
    const float* __restrict__ W_ih,   // [176][40]
    const float* __restrict__ b_ih,   // [176]
    const float* __restrict__ b_hh,   // [176]
    float* __restrict__ xproj)        // [T][B][176]
{
    const int tb = blockIdx.x;        // t*B + b
    const int gi = threadIdx.x;
    __shared__ __align__(16) float xs[IDIM];
    if (threadIdx.x < IDIM) xs[threadIdx.x] = x[(size_t)tb * IDIM + threadIdx.x];
    __syncthreads();
    if (gi < GDIM) {
        const float* wr = W_ih + gi * IDIM;
        float a0 = 0.f, a1 = 0.f;
        #pragma unroll
        for (int i = 0; i < IDIM; i += 4) {
            float4 wv = *(const float4*)&wr[i];
            float4 xv = *(const float4*)&xs[i];
            a0 += wv.x * xv.x + wv.z * xv.z;
            a1 += wv.y * xv.y + wv.w * xv.w;
        }
        const float scale = (gi >= 2 * HDIM && gi < 3 * HDIM) ? NEG_2L : NEG_L;
        xproj[(size_t)tb * GDIM + gi] = scale * (a0 + a1 + b_ih[gi] + b_hh[gi]);
    }
}

// K2: serial LSTM, TWO WAVES per batch (128-thread block).
// Wave w owns units [w*22, w*22+22). Lane-half 0 (lanes 0..21) computes gate
// rows {u, 44+u} (i,f); lane-half 1 (lanes 32..53) computes {88+u, 132+u}
// (g,o) for the same unit u. Per lane: 2 rows -> 44 pk_fma = 176 cyc issue
// (r8 calibration: pk_fma is 4cyc on wave64; r7's 88-pk block was 352 cyc,
// the dominant cost). Gate halves exchange via one shfl_xor(32) pair; both
// halves redundantly compute c,h (bit-identical); ONE LDS write + ONE
// barrier + b128 broadcast reads per step. ~165 VGPR -> no AGPR parking.
__global__ __launch_bounds__(128)
__attribute__((amdgpu_waves_per_eu(1, 1)))
void lstm_kernel(
    const float* __restrict__ xproj,  // [T][B][176] (pre-scaled)
    const float* __restrict__ h0,     // [1][B][44]
    const float* __restrict__ c0,     // [1][B][44]
    const float* __restrict__ W_hh,   // [176][44]
    const float* __restrict__ W_v,    // [1][128]
    const float* __restrict__ b_v,    // [1]
    float* __restrict__ base_out)     // [B]
{
    const int b    = blockIdx.x;
    const int tid  = threadIdx.x;      // 0..127
    const int wave = tid >> 6;         // 0,1
    const int lane = tid & 63;
    const int sub  = lane & 31;        // 0..21 active
    const int half = lane >> 5;        // 0: i,f   1: g,o
    const bool act = (sub < 22);
    const int subc = act ? sub : 21;   // clamped
    const int unit = wave * 22 + subc; // 0..43

    __shared__ __align__(16) float h_sh[64];   // h[0..43] + pad
    __shared__ float part[2];

    // rows this lane owns (both halves: row1 - row0 == 44)
    const int row0 = half ? (2 * HDIM + unit) : unit;          // g : i
    const int row1 = row0 + HDIM;                              // o : f
    const float sc0 = half ? NEG_2L : NEG_L;
    const float sc1 = NEG_L;

    // 2 weight rows in registers (44 v2f = 88 VGPR)
    v2f w0[22], w1[22];
    {
        const float* r0p = W_hh + (size_t)row0 * HDIM;
        const float* r1p = W_hh + (size_t)row1 * HDIM;
        #pragma unroll
        for (int k = 0; k < 22; ++k) {
            w0[k] = ((const v2f*)r0p)[k] * sc0;
            w1[k] = ((const v2f*)r1p)[k] * sc1;
        }
    }

    float c = c0[b * HDIM + unit];
    if (tid < HDIM) h_sh[tid] = h0[b * HDIM + tid];
    if (tid >= HDIM && tid < 64) h_sh[tid] = 0.f;
    __syncthreads();

    v2f hp[22];
    #pragma unroll
    for (int k = 0; k < 11; ++k) {
        v4f t = ((const v4f*)h_sh)[k];
        hp[2 * k]     = __builtin_shufflevector(t, t, 0, 1);
        hp[2 * k + 1] = __builtin_shufflevector(t, t, 2, 3);
    }

    // per-step xproj values for this lane's 2 rows; 2-deep prefetch
    const float* xp = xproj + (size_t)b * GDIM;
    #define LDX(d0, d1, s) { const float* _a = xp + (size_t)(s) * (BATCH * GDIM); \
        d0 = _a[row0]; d1 = _a[row1]; }
    float r0v, r1v, p0v, p1v;
    LDX(r0v, r1v, 0) LDX(p0v, p1v, 1)

    float hval = 0.f;

    #pragma unroll 1
    for (int step = 0; step < T_STEPS; ++step) {
        // 2 rows x 22 pk_fma, xc folded into acc init
        v2f a0 = {r0v, 0.f}, a1 = {r1v, 0.f};
        #pragma unroll
        for (int k = 0; k < 22; ++k) {
            a0 = __builtin_elementwise_fma(w0[k], hp[k], a0);
            a1 = __builtin_elementwise_fma(w1[k], hp[k], a1);
        }
        float y0 = a0.x + a0.y;
        float y1 = a1.x + a1.y;

        // v = rcp(1+exp2(y)) : half0 -> (sig_i, sig_f); half1 -> (w_g, sig_o)
        float v0 = __builtin_amdgcn_rcpf(1.0f + __builtin_amdgcn_exp2f(y0));
        float v1 = __builtin_amdgcn_rcpf(1.0f + __builtin_amdgcn_exp2f(y1));

        // exchange with partner lane (lane ^ 32): other half's pair
        float o0 = __shfl_xor(v0, 32);
        float o1 = __shfl_xor(v1, 32);

        // reconstruct all four (bit-identical on both halves)
        float s_i = half ? o0 : v0;
        float s_f = half ? o1 : v1;
        float w_g = half ? v0 : o0;
        float s_o = half ? v1 : o1;

        float t_g = __builtin_fmaf(2.0f, w_g, -1.0f);
        c = s_f * c + s_i * t_g;
        float w_c = __builtin_amdgcn_rcpf(1.0f + __builtin_amdgcn_exp2f(c * NEG_2L));
        hval = __builtin_fmaf(s_o + s_o, w_c, -s_o);   // s_o * tanh(c)

        // publish h: one writer per unit (half0 active lanes), one barrier
        if (act && half == 0) h_sh[unit] = hval;
        __syncthreads();

        #pragma unroll
        for (int k = 0; k < 11; ++k) {
            v4f t = ((const v4f*)h_sh)[k];
            hp[2 * k]     = __builtin_shufflevector(t, t, 0, 1);
            hp[2 * k + 1] = __builtin_shufflevector(t, t, 2, 3);
        }

        // rotate prefetch (2-deep)
        r0v = p0v; r1v = p1v;
        const int ns = (step + 2 < T_STEPS) ? step + 2 : (T_STEPS - 1);
        LDX(p0v, p1v, ns)
    }
    #undef LDX

    // epilogue: base[b] = sum_u h[u]*Wv[u] + c[u]*Wv[44+u] + b_v
    float p = 0.f;
    if (act && half == 0) p = hval * W_v[unit] + c * W_v[HDIM + unit];
    #pragma unroll
    for (int off = 32; off; off >>= 1) p += __shfl_down(p, off);
    if (lane == 0) part[wave] = p;
    __syncthreads();
    if (tid == 0) base_out[b] = part[0] + part[1] + b_v[0];
}

// K3: out[b][a] = (a < len[b]) ? base[b] + action[b][a][:].w_a : 0
__global__ __launch_bounds__(256) void action_kernel(
    const float* __restrict__ action,     // [B][A][40]
    const int*   __restrict__ act_length, // [B]
    const float* __restrict__ W_v,        // [1][128]; w_a = W_v[88..127]
    const float* __restrict__ base,       // [B]
    float* __restrict__ out)              // [B][A]
{
    const int idx = blockIdx.x * 256 + threadIdx.x;   // 0 .. B*A-1
    const int b = idx >> 18;                          // A = 2^18
    const int a = idx & (ADIM - 1);
    if (a >= act_length[b]) { out[idx] = 0.f; return; }
    const float* row = action + (size_t)idx * IDIM;
    float a0 = 0.f, a1 = 0.f;
    #pragma unroll
    for (int i = 0; i < IDIM; i += 4) {
        float4 av = *(const float4*)&row[i];
        a0 += av.x * W_v[EDIM + i + 0] + av.z * W_v[EDIM + i + 2];
        a1 += av.y * W_v[EDIM + i + 1] + av.w * W_v[EDIM + i + 3];
    }
    out[idx] = base[b] + a0 + a1;
}

extern "C" void kernel_launch(void* const* d_in, const int* in_sizes, int n_in,
                              void* d_out, int out_size, void* d_ws, size_t ws_size,
                              hipStream_t stream) {
    const float* x        = (const float*)d_in[0];
    const float* h0       = (const float*)d_in[1];
    const float* c0       = (const float*)d_in[2];
    const float* action   = (const float*)d_in[3];
    const int*   act_len  = (const int*)  d_in[4];
    const float* W_ih     = (const float*)d_in[5];
    const float* W_hh     = (const float*)d_in[6];
    const float* b_ih     = (const float*)d_in[7];
    const float* b_hh     = (const float*)d_in[8];
    const float* W_v      = (const float*)d_in[9];
    const float* b_v      = (const float*)d_in[10];
    float* out = (float*)d_out;

    float* xproj = (float*)d_ws;                                   // [T][B][176]
    float* base  = xproj + (size_t)T_STEPS * BATCH * GDIM;         // B floats

    xproj_kernel<<<dim3(T_STEPS * BATCH), dim3(192), 0, stream>>>(
        x, W_ih, b_ih, b_hh, xproj);
    lstm_kernel<<<dim3(BATCH), dim3(128), 0, stream>>>(
        xproj, h0, c0, W_hh, W_v, b_v, base);
    action_kernel<<<dim3((BATCH * ADIM) / 256), dim3(256), 0, stream>>>(
        action, act_len, W_v, base, out);
}